// Round 8
// baseline (539.800 us; speedup 1.0000x reference)
//
#include <hip/hip_runtime.h>
#include <math.h>

#define D 128
#define CT 2                       // source col-tiles (of 16) per wave
#define SRCS_PER_WAVE (CT * 16)    // 32
#define WAVES 4                    // waves per block; block covers 128 sources
#define BIAS 16.0f                 // keeps biased approx distance > 0 (u32 key ordering)
#define MROWS 64                   // target rows per macro-tile
#define BUFSZ 16640                // 16 KB A-tile + 256 B tsq tile

typedef __attribute__((ext_vector_type(8))) short short8;   // 8 bf16 = 4 VGPR
typedef __attribute__((ext_vector_type(4))) float f32x4;

// fp32 -> bf16 bits, round-to-nearest-even
static __device__ __forceinline__ unsigned short f2bf(float x) {
    unsigned u = __float_as_uint(x);
    unsigned r = u + 0x7FFFu + ((u >> 16) & 1u);
    return (unsigned short)(r >> 16);
}

// v_med3_u32: single-op per-level sorted insert primitive
static __device__ __forceinline__ unsigned med3u(unsigned a, unsigned b, unsigned c) {
    unsigned d;
    asm("v_med3_u32 %0, %1, %2, %3" : "=v"(d) : "v"(a), "v"(b), "v"(c));
    return d;
}

// exact sorted-ascending top-5 insert: 4 med3 + 1 min
static __device__ __forceinline__ void ins5(unsigned st[5], unsigned k) {
    st[4] = med3u(st[4], st[3], k);
    st[3] = med3u(st[3], st[2], k);
    st[2] = med3u(st[2], st[1], k);
    st[1] = med3u(st[1], st[0], k);
    st[0] = st[0] < k ? st[0] : k;
}

static __device__ __forceinline__ void gload_lds16(const void* g, void* l) {
    __builtin_amdgcn_global_load_lds(
        (const __attribute__((address_space(1))) unsigned*)g,
        (__attribute__((address_space(3))) unsigned*)l, 16, 0, 0);
}
static __device__ __forceinline__ void gload_lds4(const void* g, void* l) {
    __builtin_amdgcn_global_load_lds(
        (const __attribute__((address_space(1))) unsigned*)g,
        (__attribute__((address_space(3))) unsigned*)l, 4, 0, 0);
}

// Phase 0: tgt (fp32) -> tbf = bf16(-2*tgt), PRE-SWIZZLED within each 16-row tile
// (16B-unit u of row r stored at u ^ (r&15)); pad rows (M..Mpad) zeros.
// tsqb = |t|^2 + BIAS (INF pads) for the hot loop; tsqe = exact |t|^2 for refine.
__global__ void prep_kernel(const float* __restrict__ tgt, unsigned short* __restrict__ tbf,
                            float* __restrict__ tsqb, float* __restrict__ tsqe,
                            int M, int Mpad) {
    int row  = blockIdx.x;
    int lane = threadIdx.x;  // 64; handles elems 2*lane, 2*lane+1
    if (row >= Mpad) return;
    float2 v = make_float2(0.f, 0.f);
    if (row < M) v = *(const float2*)(tgt + (size_t)row * D + lane * 2);
    unsigned pack = (unsigned)f2bf(-2.f * v.x) | ((unsigned)f2bf(-2.f * v.y) << 16);
    size_t byte = (size_t)row * 256 + (size_t)(((lane >> 2) ^ (row & 15)) * 16 + (lane & 3) * 4);
    *(unsigned*)((char*)tbf + byte) = pack;
    float ss = v.x * v.x + v.y * v.y;
    #pragma unroll
    for (int off = 1; off < 64; off <<= 1) ss += __shfl_xor(ss, off);
    if (lane == 0) {
        tsqe[row] = ss;
        tsqb[row] = (row < M) ? (ss + BIAS) : __builtin_inff();
    }
}

// Main loop protocol per macro t (2 raw barriers, counted vmcnt, NO vmcnt(0)):
//   STAGE(t+1 -> buf[p^1])   (prev trailing barrier gates: all waves done READING p^1)
//   s_waitcnt vmcnt(17)      (own tile-t DMA landed; newest 17 = tile t+1)
//   s_barrier                (=> ALL waves' tile-t DMA landed)
//   compute from buf[p]      (LDS only; zero VMEM ops -> counting stays sound)
//   s_barrier                (all done reading buf[p]; next iter may overwrite)
__global__ __launch_bounds__(256, 4)
void knn_kernel(const float* __restrict__ src, const unsigned short* __restrict__ tbf,
                const float* __restrict__ tsqb, const float* __restrict__ tsqe,
                const float* __restrict__ tgt, const float* __restrict__ tpts,
                float* __restrict__ out, int N, int M, int Mpad) {
    const int tid  = (int)threadIdx.x;
    const int wid  = tid >> 6;
    const int lane = tid & 63;
    const int c16  = lane & 15;   // MFMA col (source slot) / A-row within tile
    const int g    = lane >> 4;   // row-class (C rows 4g..4g+3)
    const int colbase = blockIdx.x * (WAVES * SRCS_PER_WAVE) + wid * SRCS_PER_WAVE;

    __shared__ __align__(16) char smem[2 * BUFSZ];   // 33280 B; epilogue overlays
    float (*cdv)[16][40] = reinterpret_cast<float (*)[16][40]>(smem);                    // [WAVES][16][40]
    int   (*cjv)[16][40] = reinterpret_cast<int (*)[16][40]>(smem + WAVES * 16 * 40 * 4);

    // ---- build source (B) fragments: bf16, k = kk*32 + g*8 + e (matches A packing)
    short8 bfrag[CT][4];
    #pragma unroll
    for (int ct = 0; ct < CT; ++ct) {
        int srow = colbase + ct * 16 + c16;
        if (srow >= N) srow = N - 1;
        const float* sp = src + (size_t)srow * D + g * 8;
        #pragma unroll
        for (int kk = 0; kk < 4; ++kk) {
            float4 v0 = *(const float4*)(sp + kk * 32);
            float4 v1 = *(const float4*)(sp + kk * 32 + 4);
            short8 b;
            b[0] = (short)f2bf(v0.x); b[1] = (short)f2bf(v0.y);
            b[2] = (short)f2bf(v0.z); b[3] = (short)f2bf(v0.w);
            b[4] = (short)f2bf(v1.x); b[5] = (short)f2bf(v1.y);
            b[6] = (short)f2bf(v1.z); b[7] = (short)f2bf(v1.w);
            bfrag[ct][kk] = b;
        }
    }

    // 4 independent top-5 chains: stA[ct] takes rows 4g+{0,1}, stB[ct] rows 4g+{2,3}
    unsigned stA[CT][5], stB[CT][5];
    #pragma unroll
    for (int ct = 0; ct < CT; ++ct)
        #pragma unroll
        for (int s = 0; s < 5; ++s) { stA[ct][s] = 0xFFFFFFFFu; stB[ct][s] = 0xFFFFFFFFu; }

    // swizzled LDS element offsets (constant per thread)
    int oe[4];
    #pragma unroll
    for (int kk = 0; kk < 4; ++kk) oe[kk] = c16 * 16 + ((g + 4 * kk) ^ c16);

    const int steps = Mpad >> 6;  // 64-row macros

    #define STAGE(t, b)                                                              \
        do {                                                                         \
            const char* gA_ = (const char*)tbf + (size_t)(t) * 16384;                \
            char* lA_ = smem + (size_t)(b) * BUFSZ;                                  \
            _Pragma("unroll")                                                        \
            for (int q_ = 0; q_ < 4; ++q_) {                                         \
                int u_ = q_ * 256 + wid * 64;                                        \
                gload_lds16(gA_ + (size_t)(u_ + lane) * 16, lA_ + (size_t)u_ * 16);  \
            }                                                                        \
            gload_lds4((const char*)tsqb + (size_t)(t) * 256 + (size_t)lane * 4,     \
                       lA_ + 16384);                                                 \
        } while (0)

    unsigned jbe0 = (unsigned)(g * 4), jbe1 = jbe0 + 1, jbe2 = jbe0 + 2, jbe3 = jbe0 + 3;

    STAGE(0, 0);   // prologue: 17 loads in flight

    for (int t = 0; t < steps; ++t) {
        const int p = t & 1;
        const int tn = (t + 1 < steps) ? (t + 1) : t;
        STAGE(tn, p ^ 1);                                   // 17 more issued
        asm volatile("s_waitcnt vmcnt(17)" ::: "memory");   // own tile-t landed
        __builtin_amdgcn_s_barrier();                       // all waves' tile-t landed
        __builtin_amdgcn_sched_barrier(0);

        const short8* A = (const short8*)(smem + (size_t)p * BUFSZ);
        const float*  Q = (const float*)(smem + (size_t)p * BUFSZ + 16384);

        #define SUBSTEP(ACUR, ANXT, SUB, PREF)                                              \
            do {                                                                            \
                if (PREF) {                                                                 \
                    _Pragma("unroll")                                                       \
                    for (int kk = 0; kk < 4; ++kk) ANXT[kk] = A[((SUB) + 1) * 256 + oe[kk]];\
                }                                                                           \
                float4 q_ = *(const float4*)(Q + (SUB) * 16 + g * 4);                       \
                _Pragma("unroll")                                                           \
                for (int ct = 0; ct < CT; ++ct) {                                           \
                    f32x4 acc = { q_.x, q_.y, q_.z, q_.w };                                 \
                    _Pragma("unroll")                                                       \
                    for (int kk = 0; kk < 4; ++kk)                                          \
                        acc = __builtin_amdgcn_mfma_f32_16x16x32_bf16(ACUR[kk],             \
                                  bfrag[ct][kk], acc, 0, 0, 0);                             \
                    unsigned kA0 = (__float_as_uint(acc[0]) & 0xFFFFE000u) | jbe0;          \
                    unsigned kA1 = (__float_as_uint(acc[1]) & 0xFFFFE000u) | jbe1;          \
                    unsigned kB0 = (__float_as_uint(acc[2]) & 0xFFFFE000u) | jbe2;          \
                    unsigned kB1 = (__float_as_uint(acc[3]) & 0xFFFFE000u) | jbe3;          \
                    ins5(stA[ct], kA0); ins5(stA[ct], kA1);                                 \
                    ins5(stB[ct], kB0); ins5(stB[ct], kB1);                                 \
                }                                                                           \
                jbe0 += 16; jbe1 += 16; jbe2 += 16; jbe3 += 16;                             \
            } while (0)

        short8 aX[4], aY[4];
        #pragma unroll
        for (int kk = 0; kk < 4; ++kk) aX[kk] = A[oe[kk]];
        SUBSTEP(aX, aY, 0, 1);
        SUBSTEP(aY, aX, 1, 1);
        SUBSTEP(aX, aY, 2, 1);
        SUBSTEP(aY, aX, 3, 0);
        #undef SUBSTEP

        __builtin_amdgcn_s_barrier();   // all done reading buf[p]
    }
    #undef STAGE

    __syncthreads();   // full drain (incl. leftover prefetch) before LDS overlay

    // ---- exact fp32 refine of 40 candidates per source ----
    #pragma unroll
    for (int ct = 0; ct < CT; ++ct) {
        int js[10]; float dots[10];
        #pragma unroll
        for (int s = 0; s < 5; ++s) {
            int jA = (int)(stA[ct][s] & 0x1FFFu);
            int jB = (int)(stB[ct][s] & 0x1FFFu);
            js[s]     = (jA < M) ? jA : (M - 1);
            js[s + 5] = (jB < M) ? jB : (M - 1);
            dots[s] = 0.f; dots[s + 5] = 0.f;
        }
        int srow = colbase + ct * 16 + c16;
        int srcl = (srow < N) ? srow : (N - 1);
        const float* sp = src + (size_t)srcl * D;
        for (int kc = 0; kc < D / 16; ++kc) {
            float4 s0 = *(const float4*)(sp + kc * 16);
            float4 s1 = *(const float4*)(sp + kc * 16 + 4);
            float4 s2 = *(const float4*)(sp + kc * 16 + 8);
            float4 s3 = *(const float4*)(sp + kc * 16 + 12);
            #pragma unroll
            for (int s = 0; s < 10; ++s) {
                const float* tp = tgt + (size_t)js[s] * D + kc * 16;
                float4 t0 = *(const float4*)(tp);
                float4 t1 = *(const float4*)(tp + 4);
                float4 t2 = *(const float4*)(tp + 8);
                float4 t3 = *(const float4*)(tp + 12);
                float d = dots[s];
                d = fmaf(s0.x, t0.x, d); d = fmaf(s0.y, t0.y, d);
                d = fmaf(s0.z, t0.z, d); d = fmaf(s0.w, t0.w, d);
                d = fmaf(s1.x, t1.x, d); d = fmaf(s1.y, t1.y, d);
                d = fmaf(s1.z, t1.z, d); d = fmaf(s1.w, t1.w, d);
                d = fmaf(s2.x, t2.x, d); d = fmaf(s2.y, t2.y, d);
                d = fmaf(s2.z, t2.z, d); d = fmaf(s2.w, t2.w, d);
                d = fmaf(s3.x, t3.x, d); d = fmaf(s3.y, t3.y, d);
                d = fmaf(s3.z, t3.z, d); d = fmaf(s3.w, t3.w, d);
                dots[s] = d;
            }
        }
        #pragma unroll
        for (int s = 0; s < 10; ++s) {
            cdv[wid][c16][g * 10 + s] = fmaf(-2.f, dots[s], tsqe[js[s]]);
            cjv[wid][c16][g * 10 + s] = js[s];
        }
        __syncthreads();
        if (g == 0) {
            float d0 = __builtin_inff(), d1 = d0, d2 = d0;
            int i0 = 0, i1 = 0, i2 = 0;
            for (int k = 0; k < 40; ++k) {
                float dd = cdv[wid][c16][k]; int jj = cjv[wid][c16][k];
                if (dd < d2) {
                    if (dd < d1) {
                        d2 = d1; i2 = i1;
                        if (dd < d0) { d1 = d0; i1 = i0; d0 = dd; i0 = jj; }
                        else         { d1 = dd; i1 = jj; }
                    } else { d2 = dd; i2 = jj; }
                }
            }
            if (srow < N) {
                float e1 = __expf(d0 - d1);
                float e2 = __expf(d0 - d2);
                float inv = 1.f / (1.f + e1 + e2);
                float w0 = inv, w1 = e1 * inv, w2 = e2 * inv;
                const float* p0 = tpts + 3 * (size_t)i0;
                const float* p1 = tpts + 3 * (size_t)i1;
                const float* p2 = tpts + 3 * (size_t)i2;
                out[3 * (size_t)srow + 0] = w0 * p0[0] + w1 * p1[0] + w2 * p2[0];
                out[3 * (size_t)srow + 1] = w0 * p0[1] + w1 * p1[1] + w2 * p2[1];
                out[3 * (size_t)srow + 2] = w0 * p0[2] + w1 * p1[2] + w2 * p2[2];
            }
        }
        __syncthreads();
    }
}

extern "C" void kernel_launch(void* const* d_in, const int* in_sizes, int n_in,
                              void* d_out, int out_size, void* d_ws, size_t ws_size,
                              hipStream_t stream) {
    const float* src  = (const float*)d_in[0];  // [N,128]
    const float* tgt  = (const float*)d_in[1];  // [M,128]
    const float* tpts = (const float*)d_in[2];  // [M,3]
    float* out = (float*)d_out;

    int N = in_sizes[0] / D;
    int M = in_sizes[1] / D;
    int Mpad = (M + 63) & ~63;                  // 64-row macro-tiles

    unsigned short* tbf = (unsigned short*)d_ws;                      // Mpad*128 bf16 (-2t), swizzled
    float* tsqb = (float*)((char*)d_ws + (size_t)Mpad * D * 2);       // Mpad f32: |t|^2+BIAS (INF pads)
    float* tsqe = (float*)((char*)d_ws + (size_t)Mpad * D * 2 + (size_t)Mpad * 4);  // exact |t|^2

    prep_kernel<<<Mpad, 64, 0, stream>>>(tgt, tbf, tsqb, tsqe, M, Mpad);
    int per_block = WAVES * SRCS_PER_WAVE;                            // 128
    int nblk = (N + per_block - 1) / per_block;                       // 782
    knn_kernel<<<nblk, 256, 0, stream>>>(src, tbf, tsqb, tsqe, tgt, tpts, out, N, M, Mpad);
}

// Round 9
// 391.872 us; speedup vs baseline: 1.3775x; 1.3775x over previous
//
#include <hip/hip_runtime.h>
#include <math.h>

#define D 128
#define CT 2                       // source col-tiles (of 16) per wave
#define SRCS_PER_WAVE (CT * 16)    // 32
#define WAVES 4                    // waves per block; block covers 128 sources
#define BIAS 16.0f                 // keeps biased approx distance > 0 (u32 key ordering)
#define REFK 10                    // exact-refine candidates per source

typedef __attribute__((ext_vector_type(8))) short short8;   // 8 bf16 = 4 VGPR
typedef __attribute__((ext_vector_type(4))) float f32x4;

// fp32 -> bf16 bits, round-to-nearest-even
static __device__ __forceinline__ unsigned short f2bf(float x) {
    unsigned u = __float_as_uint(x);
    unsigned r = u + 0x7FFFu + ((u >> 16) & 1u);
    return (unsigned short)(r >> 16);
}

// v_med3_u32: single-op per-level sorted insert primitive
static __device__ __forceinline__ unsigned med3u(unsigned a, unsigned b, unsigned c) {
    unsigned d;
    asm("v_med3_u32 %0, %1, %2, %3" : "=v"(d) : "v"(a), "v"(b), "v"(c));
    return d;
}

// exact sorted-ascending top-5 insert: 4 med3 + 1 min
static __device__ __forceinline__ void ins5(unsigned st[5], unsigned k) {
    st[4] = med3u(st[4], st[3], k);
    st[3] = med3u(st[3], st[2], k);
    st[2] = med3u(st[2], st[1], k);
    st[1] = med3u(st[1], st[0], k);
    st[0] = st[0] < k ? st[0] : k;
}

// exact sorted-ascending top-10 insert: 9 med3 + 1 min
static __device__ __forceinline__ void ins10(unsigned st[REFK], unsigned k) {
    #pragma unroll
    for (int s = REFK - 1; s >= 1; --s) st[s] = med3u(st[s], st[s - 1], k);
    st[0] = st[0] < k ? st[0] : k;
}

static __device__ __forceinline__ void gload_lds16(const void* g, void* l) {
    __builtin_amdgcn_global_load_lds(
        (const __attribute__((address_space(1))) unsigned*)g,
        (__attribute__((address_space(3))) unsigned*)l, 16, 0, 0);
}

// Phase 0: tgt (fp32) -> tbf = bf16(-2*tgt), PRE-SWIZZLED within each 16-row tile
// (16B-unit u of row r stored at u ^ (r&15)); pad rows (M..Mpad) zeros.
// tsqb = |t|^2 + BIAS (INF pads) for the hot loop; tsqe = exact |t|^2 for refine.
__global__ void prep_kernel(const float* __restrict__ tgt, unsigned short* __restrict__ tbf,
                            float* __restrict__ tsqb, float* __restrict__ tsqe,
                            int M, int Mpad) {
    int row  = blockIdx.x;
    int lane = threadIdx.x;  // 64; handles elems 2*lane, 2*lane+1
    if (row >= Mpad) return;
    float2 v = make_float2(0.f, 0.f);
    if (row < M) v = *(const float2*)(tgt + (size_t)row * D + lane * 2);
    unsigned pack = (unsigned)f2bf(-2.f * v.x) | ((unsigned)f2bf(-2.f * v.y) << 16);
    size_t byte = (size_t)row * 256 + (size_t)(((lane >> 2) ^ (row & 15)) * 16 + (lane & 3) * 4);
    *(unsigned*)((char*)tbf + byte) = pack;
    float ss = v.x * v.x + v.y * v.y;
    #pragma unroll
    for (int off = 1; off < 64; off <<= 1) ss += __shfl_xor(ss, off);
    if (lane == 0) {
        tsqe[row] = ss;
        tsqb[row] = (row < M) ? (ss + BIAS) : __builtin_inff();
    }
}

// Scan: round-7 core. Each block (blockIdx.y = half) sweeps HALF the targets.
// A = targets (64-row macros, LDS double-buffered, __syncthreads protocol),
// B = sources (register-resident). Output: top-5 packed keys
// (dist bits | 13-bit j) per (source, row-class, half) -> keys[src][half*20+g*5+s].
__global__ __launch_bounds__(256, 4)
void knn_scan(const float* __restrict__ src, const unsigned short* __restrict__ tbf,
              const float* __restrict__ tsqb, unsigned* __restrict__ keys,
              int N, int M, int h0, int msteps) {
    const int tid  = (int)threadIdx.x;
    const int wid  = tid >> 6;
    const int lane = tid & 63;
    const int c16  = lane & 15;   // MFMA col (source slot) / A-row within tile
    const int g    = lane >> 4;   // row-class (C rows 4g..4g+3)
    const int half = blockIdx.y;
    const int colbase = blockIdx.x * (WAVES * SRCS_PER_WAVE) + wid * SRCS_PER_WAVE;

    __shared__ __align__(16) short8 abuf[2][1024];   // 2 x 16KB macro-tiles = 32 KB

    // ---- build source (B) fragments: bf16, k = kk*32 + g*8 + e (matches A packing)
    short8 bfrag[CT][4];
    #pragma unroll
    for (int ct = 0; ct < CT; ++ct) {
        int srow = colbase + ct * 16 + c16;
        if (srow >= N) srow = N - 1;
        const float* sp = src + (size_t)srow * D + g * 8;
        #pragma unroll
        for (int kk = 0; kk < 4; ++kk) {
            float4 v0 = *(const float4*)(sp + kk * 32);
            float4 v1 = *(const float4*)(sp + kk * 32 + 4);
            short8 b;
            b[0] = (short)f2bf(v0.x); b[1] = (short)f2bf(v0.y);
            b[2] = (short)f2bf(v0.z); b[3] = (short)f2bf(v0.w);
            b[4] = (short)f2bf(v1.x); b[5] = (short)f2bf(v1.y);
            b[6] = (short)f2bf(v1.z); b[7] = (short)f2bf(v1.w);
            bfrag[ct][kk] = b;
        }
    }

    unsigned st[CT][5];
    #pragma unroll
    for (int ct = 0; ct < CT; ++ct)
        #pragma unroll
        for (int s = 0; s < 5; ++s) st[ct][s] = 0xFFFFFFFFu;

    // swizzled LDS element offsets (constant per thread)
    int oe[4];
    #pragma unroll
    for (int kk = 0; kk < 4; ++kk) oe[kk] = c16 * 16 + ((g + 4 * kk) ^ c16);

    const int t0 = half ? h0 : 0;
    const int tc = half ? (msteps - h0) : h0;   // macros in this half

    #define STAGE(t, b)                                                              \
        do {                                                                         \
            const char* gbase_ = (const char*)tbf + (size_t)(t) * 16384;             \
            _Pragma("unroll")                                                        \
            for (int q_ = 0; q_ < 4; ++q_) {                                         \
                int uoff_ = q_ * 256 + wid * 64;                                     \
                gload_lds16(gbase_ + ((size_t)(uoff_ + lane)) * 16,                  \
                            (void*)&abuf[b][uoff_]);                                 \
            }                                                                        \
        } while (0)

    float4 qv[4], qn[4];
    #pragma unroll
    for (int s = 0; s < 4; ++s)
        qv[s] = *(const float4*)(tsqb + (size_t)t0 * 64 + s * 16 + g * 4);
    STAGE(t0, 0);
    __syncthreads();

    unsigned jb = (unsigned)(t0 * 64 + g * 4);
    int cur = 0;
    for (int tt = 0; tt < tc; ++tt) {
        int tn = t0 + ((tt + 1 < tc) ? (tt + 1) : tt);
        STAGE(tn, cur ^ 1);
        #pragma unroll
        for (int s = 0; s < 4; ++s)
            qn[s] = *(const float4*)(tsqb + (size_t)tn * 64 + s * 16 + g * 4);

        #pragma unroll
        for (int sub = 0; sub < 4; ++sub) {
            short8 a[4];
            #pragma unroll
            for (int kk = 0; kk < 4; ++kk)
                a[kk] = abuf[cur][sub * 256 + oe[kk]];
            #pragma unroll
            for (int ct = 0; ct < CT; ++ct) {
                f32x4 acc = { qv[sub].x, qv[sub].y, qv[sub].z, qv[sub].w };
                #pragma unroll
                for (int kk = 0; kk < 4; ++kk)
                    acc = __builtin_amdgcn_mfma_f32_16x16x32_bf16(a[kk], bfrag[ct][kk], acc, 0, 0, 0);
                #pragma unroll
                for (int e = 0; e < 4; ++e) {
                    unsigned key = (__float_as_uint(acc[e]) & 0xFFFFE000u) | (jb + (unsigned)e);
                    ins5(st[ct], key);
                }
            }
            jb += 16;
        }
        #pragma unroll
        for (int s = 0; s < 4; ++s) qv[s] = qn[s];
        __syncthreads();   // drains vmcnt(0): next macro staged; buf[cur] consumed
        cur ^= 1;
    }
    #undef STAGE

    // ---- emit candidate keys ----
    #pragma unroll
    for (int ct = 0; ct < CT; ++ct) {
        int srow = colbase + ct * 16 + c16;
        if (srow < N) {
            #pragma unroll
            for (int s = 0; s < 5; ++s)
                keys[(size_t)srow * 40 + half * 20 + g * 5 + s] = st[ct][s];
        }
    }
}

// Merge: 1 thread per source. Top-10 (by truncated bf16 key) of the 40
// candidates, exact fp32 refine of those 10, top-3 + softmax + output.
__global__ __launch_bounds__(256, 4)
void knn_merge(const float* __restrict__ src, const float* __restrict__ tgt,
               const float* __restrict__ tsqe, const unsigned* __restrict__ keys,
               const float* __restrict__ tpts, float* __restrict__ out,
               int N, int M) {
    int i = blockIdx.x * 256 + (int)threadIdx.x;
    if (i >= N) return;

    unsigned best[REFK];
    #pragma unroll
    for (int s = 0; s < REFK; ++s) best[s] = 0xFFFFFFFFu;

    const uint4* kp = (const uint4*)(keys + (size_t)i * 40);
    #pragma unroll
    for (int q = 0; q < 10; ++q) {
        uint4 kv = kp[q];
        ins10(best, kv.x); ins10(best, kv.y); ins10(best, kv.z); ins10(best, kv.w);
    }

    int js[REFK]; float dt[REFK];
    #pragma unroll
    for (int s = 0; s < REFK; ++s) {
        int j = (int)(best[s] & 0x1FFFu);
        js[s] = (j < M) ? j : (M - 1);
        dt[s] = 0.f;
    }

    const float4* sp = (const float4*)(src + (size_t)i * D);
    for (int kc = 0; kc < D / 4; ++kc) {
        float4 sv = sp[kc];
        #pragma unroll
        for (int s = 0; s < REFK; ++s) {
            float4 tv = *(const float4*)(tgt + (size_t)js[s] * D + kc * 4);
            dt[s] = fmaf(sv.x, tv.x, fmaf(sv.y, tv.y, fmaf(sv.z, tv.z, fmaf(sv.w, tv.w, dt[s]))));
        }
    }

    float d0 = __builtin_inff(), d1 = d0, d2 = d0;
    int i0 = 0, i1 = 0, i2 = 0;
    #pragma unroll
    for (int s = 0; s < REFK; ++s) {
        float dd = fmaf(-2.f, dt[s], tsqe[js[s]]);
        int jj = js[s];
        if (dd < d2) {
            if (dd < d1) {
                d2 = d1; i2 = i1;
                if (dd < d0) { d1 = d0; i1 = i0; d0 = dd; i0 = jj; }
                else         { d1 = dd; i1 = jj; }
            } else { d2 = dd; i2 = jj; }
        }
    }

    float e1 = __expf(d0 - d1);
    float e2 = __expf(d0 - d2);
    float inv = 1.f / (1.f + e1 + e2);
    float w0 = inv, w1 = e1 * inv, w2 = e2 * inv;
    const float* p0 = tpts + 3 * (size_t)i0;
    const float* p1 = tpts + 3 * (size_t)i1;
    const float* p2 = tpts + 3 * (size_t)i2;
    out[3 * (size_t)i + 0] = w0 * p0[0] + w1 * p1[0] + w2 * p2[0];
    out[3 * (size_t)i + 1] = w0 * p0[1] + w1 * p1[1] + w2 * p2[1];
    out[3 * (size_t)i + 2] = w0 * p0[2] + w1 * p1[2] + w2 * p2[2];
}

extern "C" void kernel_launch(void* const* d_in, const int* in_sizes, int n_in,
                              void* d_out, int out_size, void* d_ws, size_t ws_size,
                              hipStream_t stream) {
    const float* src  = (const float*)d_in[0];  // [N,128]
    const float* tgt  = (const float*)d_in[1];  // [M,128]
    const float* tpts = (const float*)d_in[2];  // [M,3]
    float* out = (float*)d_out;

    int N = in_sizes[0] / D;
    int M = in_sizes[1] / D;
    int Mpad = (M + 63) & ~63;                  // 64-row macro-tiles
    int msteps = Mpad >> 6;                     // 108
    int h0 = (msteps + 1) >> 1;                 // 54 macros in half 0

    // ws layout: tbf (Mpad*256 B, swizzled) | tsqb (Mpad*4) | tsqe (Mpad*4) |
    //            keys (N*40*4 = 16 MB). Total ~17.8 MB.
    char* w = (char*)d_ws;
    unsigned short* tbf = (unsigned short*)w;                 w += (size_t)Mpad * 256;
    float* tsqb = (float*)w;                                  w += (size_t)Mpad * 4;
    float* tsqe = (float*)w;                                  w += (size_t)Mpad * 4;
    unsigned* keys = (unsigned*)w;

    prep_kernel<<<Mpad, 64, 0, stream>>>(tgt, tbf, tsqb, tsqe, M, Mpad);

    int per_block = WAVES * SRCS_PER_WAVE;                    // 128
    dim3 sgrid((N + per_block - 1) / per_block, 2);           // 782 x 2 = 1564 blocks
    knn_scan<<<sgrid, 256, 0, stream>>>(src, tbf, tsqb, keys, N, M, h0, msteps);

    knn_merge<<<(N + 255) / 256, 256, 0, stream>>>(src, tgt, tsqe, keys, tpts, out, N, M);
}